// Round 25
// baseline (85.414 us; speedup 1.0000x reference)
//
#include <hip/hip_runtime.h>
#include <hip/hip_bf16.h>
#include <math.h>

#define Bb   4
#define Hh   16
#define Tt   4096
#define Dd   64
#define Pp   128
#define MAXN 32
#define BHc  64   // B*H

typedef _Float16 f16x8 __attribute__((ext_vector_type(8)));
typedef _Float16 f16x4 __attribute__((ext_vector_type(4)));
typedef float    f32x4 __attribute__((ext_vector_type(4)));

// swizzled element index into a [row][64] fp16 LDS tile
#define SW64(row, col) (((row) * 64) + ((col) ^ (((row) & 7) << 3)))

// inv_freq in f32: 10000^(-fi/16) = exp2(-fi * log2(10000)/16)
__device__ __forceinline__ float inv_freq(int fi) {
    return exp2f(-(float)fi * 0.83048201f);
}

// ---------------- precompute: cos/sin table for global positions (all-f32) ----------------
__global__ void k_postab(float* __restrict__ postab) {
    int idx = blockIdx.x * blockDim.x + threadIdx.x;
    if (idx >= Tt * 16) return;
    int pos = idx >> 4, fi = idx & 15;
    float ang = (float)pos * inv_freq(fi);
    postab[idx * 2 + 0] = cosf(ang);
    postab[idx * 2 + 1] = sinf(ang);
}

// ---------------- precompute: region starts + region cos/sin table (all-f32) ----------------
__global__ void k_prep(const int* __restrict__ regions, float* __restrict__ regtab,
                       int* __restrict__ starts) {
    int i = threadIdx.x;
    if (i < Bb * MAXN) {
        int b = i >> 5, n = (i & 31) + 1;
        const int* r = regions + b * Tt;
        int lo = 0, hi = Tt;
        while (lo < hi) { int mid = (lo + hi) >> 1; if (r[mid] < n) lo = mid + 1; else hi = mid; }
        starts[i] = (lo < Tt && r[lo] == n) ? lo : 0;
    }
    int j = i - Bb * MAXN;
    if (j >= 0 && j < 33 * 16) {
        int pos = j >> 4, fi = j & 15;
        float ang = (float)pos * inv_freq(fi);
        regtab[j * 2 + 0] = cosf(ang);
        regtab[j * 2 + 1] = sinf(ang);
    }
}

// ---------------- main kernel: r24 structure, fp16 partial pO ----------------
__global__ __launch_bounds__(512) void k_attn(
    const float* __restrict__ q_in, const float* __restrict__ k_in,
    const float* __restrict__ v_in, const int* __restrict__ regions,
    const float* __restrict__ bias_same, const float* __restrict__ bias_diff,
    const float* __restrict__ postab, const float* __restrict__ regtab,
    const int* __restrict__ starts, _Float16* __restrict__ pO,
    float* __restrict__ pML, int NS)
{
    const int bid   = blockIdx.x;
    const int chunk = bid % NS;
    const int bh    = bid / NS;
    const int b     = bh >> 4;
    const int h     = bh & 15;
    const int C     = Tt / NS;
    const int NTILE = C >> 6;
    const int c0    = chunk * C;

    const int tid = threadIdx.x;
    const int w  = tid >> 6;        // wave 0..7, owns p cols [16w, 16w+16)
    const int l  = tid & 63;
    const int cl = l & 15;
    const int g  = l >> 4;

    __shared__ __align__(16) _Float16 Qs[Pp * 64];    // q fp16, PERSISTENT
    __shared__ __align__(16) _Float16 Ks[64 * 64];    // k fp16
    __shared__ __align__(16) _Float16 Vs[64 * 64];    // v fp16, [d][t]
    __shared__ __align__(16) _Float16 Ps[Pp * 64];    // p fp16, wave-private rows
    __shared__ __align__(16) float rtab[33 * 16 * 2];
    __shared__ int regs_s[64];
    __shared__ int starts_s[MAXN];

    for (int j = tid; j < 33 * 16 * 2; j += 512) rtab[j] = regtab[j];
    if (tid < MAXN) starts_s[tid] = starts[b * MAXN + tid];
    const float bs = bias_same[h];
    const float bd = bias_diff[h];
    __syncthreads();

    // ---- stage Q (rope, fp16) into persistent Qs ----
    const float* Qbh = q_in + (size_t)bh * Pp * Dd;
#pragma unroll
    for (int it = 0; it < 4; ++it) {
        int f  = tid + 512 * it;
        int p  = f >> 4;
        int dq = (f & 15) << 2;
        float4 x = ((const float4*)Qbh)[f];
        int fi = (dq & 31) >> 1;
        float4 cs;
        if (dq < 32) {
            int gpos = starts_s[p >> 2];
            cs = *(const float4*)(postab + (size_t)(gpos * 16 + fi) * 2);
        } else {
            int ridx = (p >> 2) + 1;
            cs = *(const float4*)(&rtab[(ridx * 16 + fi) * 2]);
        }
        f16x4 hh;
        hh[0] = (_Float16)(x.x * cs.x - x.y * cs.y);
        hh[1] = (_Float16)(x.x * cs.y + x.y * cs.x);
        hh[2] = (_Float16)(x.z * cs.z - x.w * cs.w);
        hh[3] = (_Float16)(x.z * cs.w + x.w * cs.z);
        *(f16x4*)(Qs + SW64(p, dq)) = hh;
    }
    __syncthreads();

    // ---- Q fragments from LDS (persistent source), 16 cols per wave ----
    f16x8 qh[2];
    {
        int pr = w * 16 + cl;
#pragma unroll
        for (int ks = 0; ks < 2; ++ks)
            qh[ks] = *(const f16x8*)(Qs + SW64(pr, ks * 32 + g * 8));
    }

    float m0 = -INFINITY, l0 = 0.f;
    f32x4 Oacc[4];
#pragma unroll
    for (int i1 = 0; i1 < 4; ++i1) Oacc[i1] = (f32x4)0.f;

    const float* Kbh = k_in + (size_t)bh * Tt * Dd;
    const float* Vbh = v_in + (size_t)bh * Tt * Dd;

    // ---- T14 prefetch state: next tile's raw data in registers (V packed fp16) ----
    float4 kx[2], kcs[2];
    int    krg[2], rreg;
    f16x8  vx16;
    auto prefetch = [&](int t0n) {
#pragma unroll
        for (int it = 0; it < 2; ++it) {
            int f   = tid + 512 * it;
            int row = f >> 4;
            int dq  = (f & 15) << 2;
            int fi  = (dq & 31) >> 1;
            kx[it]  = ((const float4*)(Kbh + (size_t)t0n * Dd))[f];
            kcs[it] = *(const float4*)(postab + (size_t)((t0n + row) * 16 + fi) * 2);
            krg[it] = regions[b * Tt + t0n + row];
        }
        {
            int dcol = tid & 63;
            int tl   = (tid >> 6) * 8;
#pragma unroll
            for (int r = 0; r < 8; ++r)
                vx16[r] = (_Float16)Vbh[(size_t)(t0n + tl + r) * Dd + dcol];
        }
        rreg = (tid < 64) ? regions[b * Tt + t0n + tid] : 0;
    };
    prefetch(c0);

    for (int tt = 0; tt < NTILE; ++tt) {
        const int t0 = c0 + tt * 64;
        __syncthreads();   // B1: previous tile fully consumed
        if (tid < 64) regs_s[tid] = rreg;

        // ---- convert prefetched K tile: rope fp16 -> LDS ----
#pragma unroll
        for (int it = 0; it < 2; ++it) {
            int f   = tid + 512 * it;
            int row = f >> 4;
            int dq  = (f & 15) << 2;
            float4 x = kx[it];
            float4 cs;
            if (dq < 32) {
                cs = kcs[it];
            } else {
                int rg = krg[it];
                cs = *(const float4*)(&rtab[(rg * 16 + ((dq & 31) >> 1)) * 2]);
            }
            f16x4 hh;
            hh[0] = (_Float16)(x.x * cs.x - x.y * cs.y);
            hh[1] = (_Float16)(x.x * cs.y + x.y * cs.x);
            hh[2] = (_Float16)(x.z * cs.z - x.w * cs.w);
            hh[3] = (_Float16)(x.z * cs.w + x.w * cs.z);
            *(f16x4*)(Ks + SW64(row, dq)) = hh;
        }

        // ---- write prefetched V tile (already fp16) -> LDS ----
        {
            int dcol = tid & 63;
            int tl   = (tid >> 6) * 8;
            *(f16x8*)(Vs + SW64(dcol, tl)) = vx16;
        }
        __syncthreads();   // B2: staging complete

        // ---- issue next tile's loads (latency hides under this tile's compute) ----
        if (tt + 1 < NTILE) prefetch(t0 + 64);

        // ---- QK^T MFMA, 2 k-steps (single fp16), setprio-wrapped ----
        f32x4 sacc[4];
#pragma unroll
        for (int mt = 0; mt < 4; ++mt) sacc[mt] = (f32x4)0.f;
        __builtin_amdgcn_s_setprio(1);
#pragma unroll
        for (int s = 0; s < 2; ++s) {
            f16x8 b0 = qh[s];
#pragma unroll
            for (int mt = 0; mt < 4; ++mt) {
                int tr = mt * 16 + cl;
                f16x8 ak = *(const f16x8*)(Ks + SW64(tr, s * 32 + g * 8));
                sacc[mt] = __builtin_amdgcn_mfma_f32_16x16x32_f16(ak, b0, sacc[mt], 0, 0, 0);
            }
        }
        __builtin_amdgcn_s_setprio(0);

        // ---- scale + bias; per-column (p) tile max ----
        float tmax0 = -INFINITY;
        const int ridx0 = ((w * 16 + cl) >> 2) + 1;
#pragma unroll
        for (int mt = 0; mt < 4; ++mt) {
#pragma unroll
            for (int r = 0; r < 4; ++r) {
                int rg = regs_s[mt * 16 + g * 4 + r];
                float s0 = sacc[mt][r] * 0.125f + ((ridx0 == rg) ? bs : bd);
                sacc[mt][r] = s0;
                tmax0 = fmaxf(tmax0, s0);
            }
        }
        tmax0 = fmaxf(tmax0, __shfl_xor(tmax0, 16, 64));
        tmax0 = fmaxf(tmax0, __shfl_xor(tmax0, 32, 64));
        float mn0 = fmaxf(m0, tmax0);
        float sc0 = __expf(m0 - mn0);

        // ---- P = exp(s - m_new) -> fp16 -> LDS (wave-private rows); f32 row sums ----
        float rs0 = 0.f;
#pragma unroll
        for (int mt = 0; mt < 4; ++mt) {
            f16x4 ph0;
#pragma unroll
            for (int r = 0; r < 4; ++r) {
                float e0 = __expf(sacc[mt][r] - mn0);
                rs0 += e0;
                ph0[r] = (_Float16)e0;
            }
            int trow = mt * 16 + g * 4;
            int pa = w * 16 + cl;
            *(f16x4*)(Ps + SW64(pa, trow)) = ph0;
        }
        rs0 += __shfl_xor(rs0, 16, 64); rs0 += __shfl_xor(rs0, 32, 64);
        l0 = l0 * sc0 + rs0; m0 = mn0;

        // P rows are wave-private: drain this wave's LDS writes, no block barrier
        asm volatile("s_waitcnt lgkmcnt(0)" ::: "memory");
        __builtin_amdgcn_sched_barrier(0);

        // ---- rescale O (factor per output row p = w*16 + g*4 + r) ----
#pragma unroll
        for (int r = 0; r < 4; ++r) {
            float f0 = __shfl(sc0, g * 4 + r, 64);
#pragma unroll
            for (int nt = 0; nt < 4; ++nt) Oacc[nt][r] *= f0;
        }

        // ---- PV: O += P·V (fp16, 2 k-steps), setprio-wrapped ----
        __builtin_amdgcn_s_setprio(1);
#pragma unroll
        for (int s = 0; s < 2; ++s) {
            f16x8 ap0;
            {
                int pp = w * 16 + cl;
                ap0 = *(const f16x8*)(Ps + SW64(pp, s * 32 + g * 8));
            }
#pragma unroll
            for (int nt = 0; nt < 4; ++nt) {
                int d = nt * 16 + cl;
                f16x8 bv = *(const f16x8*)(Vs + SW64(d, s * 32 + g * 8));
                Oacc[nt] = __builtin_amdgcn_mfma_f32_16x16x32_f16(ap0, bv, Oacc[nt], 0, 0, 0);
            }
        }
        __builtin_amdgcn_s_setprio(0);
    }

    // ---- write partials (fp16 pO; m,l stay f32) ----
    size_t obase = (size_t)(bh * NS + chunk) * Pp * Dd;
#pragma unroll
    for (int nt = 0; nt < 4; ++nt)
#pragma unroll
        for (int r = 0; r < 4; ++r) {
            int pb = w * 16 + g * 4 + r;
            int d  = nt * 16 + cl;
            pO[obase + pb * 64 + d] = (_Float16)Oacc[nt][r];
        }
    if (g == 0) {
        size_t mlb = (size_t)(bh * NS + chunk) * Pp;
        int p0 = w * 16 + cl;
        *(float2*)(pML + (mlb + p0) * 2) = make_float2(m0, l0);
    }
}

// ---------------- combine partials across T-chunks (fp16 pO) ----------------
__global__ void k_combine(const _Float16* __restrict__ pO, const float* __restrict__ pML,
                          float* __restrict__ out, int NS) {
    int bh = blockIdx.x >> 2;
    int pq = blockIdx.x & 3;
    int d  = threadIdx.x & 63;
    int ps = threadIdx.x >> 6;
    for (int pp = 0; pp < 8; ++pp) {
        int p = pq * 32 + pp * 4 + ps;
        float M = -INFINITY;
        float mv[8], lv[8];
        for (int c = 0; c < NS; ++c) {
            float2 ml = *(const float2*)(pML + ((size_t)(bh * NS + c) * Pp + p) * 2);
            mv[c] = ml.x; lv[c] = ml.y;
            M = fmaxf(M, ml.x);
        }
        float L = 0.f, o = 0.f;
        for (int c = 0; c < NS; ++c) {
            float wgt = __expf(mv[c] - M);
            L += wgt * lv[c];
            o += wgt * (float)pO[((size_t)(bh * NS + c) * Pp + p) * Dd + d];
        }
        out[((size_t)bh * Pp + p) * Dd + d] = o / L;
    }
}

// ---------------- launcher ----------------
extern "C" void kernel_launch(void* const* d_in, const int* in_sizes, int n_in,
                              void* d_out, int out_size, void* d_ws, size_t ws_size,
                              hipStream_t stream) {
    const float* q         = (const float*)d_in[0];
    const float* k         = (const float*)d_in[1];
    const float* v         = (const float*)d_in[2];
    const int*   regions   = (const int*)d_in[3];
    const float* bias_same = (const float*)d_in[7];
    const float* bias_diff = (const float*)d_in[8];

    float* ws     = (float*)d_ws;
    float* postab = ws;
    float* regtab = postab + Tt * 16 * 2;
    int*   starts = (int*)(regtab + 33 * 16 * 2);
    _Float16* pO  = (_Float16*)(starts + 128);
    size_t fixed_b = (size_t)((char*)pO - (char*)ws);

    int NS = 8;   // grid 512 = 2 blocks/CU resident (52.5 KB LDS)
    // bytes: pO fp16 (Dd*2 B/row) + pML f32 (8 B/row)
    while (NS > 1 && fixed_b + (size_t)BHc * NS * Pp * (Dd * 2 + 8) > ws_size) NS >>= 1;
    float* pML = (float*)(pO + (size_t)BHc * NS * Pp * Dd);

    k_postab<<<dim3(Tt * 16 / 256), dim3(256), 0, stream>>>(postab);
    k_prep<<<dim3(1), dim3(704), 0, stream>>>(regions, regtab, starts);
    k_attn<<<dim3(BHc * NS), dim3(512), 0, stream>>>(q, k, v, regions, bias_same, bias_diff,
                                                     postab, regtab, starts, pO, pML, NS);
    k_combine<<<dim3(BHc * 4), dim3(256), 0, stream>>>(pO, pML, (float*)d_out, NS);
}

// Round 26
// 57.138 us; speedup vs baseline: 1.4949x; 1.4949x over previous
//
#include <hip/hip_runtime.h>
#include <hip/hip_bf16.h>
#include <math.h>

#define Bb   4
#define Hh   16
#define Tt   4096
#define Dd   64
#define Pp   128
#define MAXN 32
#define BHc  64   // B*H

typedef _Float16 f16x8 __attribute__((ext_vector_type(8)));
typedef _Float16 f16x4 __attribute__((ext_vector_type(4)));
typedef float    f32x4 __attribute__((ext_vector_type(4)));

// swizzled element index into a [row][64] fp16 LDS tile
#define SW64(row, col) (((row) * 64) + ((col) ^ (((row) & 7) << 3)))

// inv_freq in f32: 10000^(-fi/16) = exp2(-fi * log2(10000)/16)
__device__ __forceinline__ float inv_freq(int fi) {
    return exp2f(-(float)fi * 0.83048201f);
}

// ---------------- merged prelude: postab (blocks 0..255) + starts/regtab (block 256) ----------------
__global__ void k_prelude(const int* __restrict__ regions, float* __restrict__ postab,
                          float* __restrict__ regtab, int* __restrict__ starts) {
    int bidx = blockIdx.x;
    int tid  = threadIdx.x;
    if (bidx < 256) {
        int idx = bidx * 256 + tid;           // < 65536 = Tt*16
        int pos = idx >> 4, fi = idx & 15;
        float ang = (float)pos * inv_freq(fi);
        postab[idx * 2 + 0] = cosf(ang);
        postab[idx * 2 + 1] = sinf(ang);
        return;
    }
    // block 256: region starts (binary search on sorted regions) + regtab
    if (tid < Bb * MAXN) {
        int b = tid >> 5, n = (tid & 31) + 1;
        const int* r = regions + b * Tt;
        int lo = 0, hi = Tt;
        while (lo < hi) { int mid = (lo + hi) >> 1; if (r[mid] < n) lo = mid + 1; else hi = mid; }
        starts[tid] = (lo < Tt && r[lo] == n) ? lo : 0;
    }
    for (int j = tid; j < 33 * 16; j += 256) {
        int pos = j >> 4, fi = j & 15;
        float ang = (float)pos * inv_freq(fi);
        regtab[j * 2 + 0] = cosf(ang);
        regtab[j * 2 + 1] = sinf(ang);
    }
}

// ---------------- main kernel: BYTE-IDENTICAL math to r25 (best-known-good) ----------------
__global__ __launch_bounds__(512) void k_attn(
    const float* __restrict__ q_in, const float* __restrict__ k_in,
    const float* __restrict__ v_in, const int* __restrict__ regions,
    const float* __restrict__ bias_same, const float* __restrict__ bias_diff,
    const float* __restrict__ postab, const float* __restrict__ regtab,
    const int* __restrict__ starts, _Float16* __restrict__ pO,
    float* __restrict__ pML, int NS)
{
    const int bid   = blockIdx.x;
    const int chunk = bid % NS;
    const int bh    = bid / NS;
    const int b     = bh >> 4;
    const int h     = bh & 15;
    const int C     = Tt / NS;
    const int NTILE = C >> 6;
    const int c0    = chunk * C;

    const int tid = threadIdx.x;
    const int w  = tid >> 6;        // wave 0..7, owns p cols [16w, 16w+16)
    const int l  = tid & 63;
    const int cl = l & 15;
    const int g  = l >> 4;

    __shared__ __align__(16) _Float16 Qs[Pp * 64];    // q fp16, PERSISTENT
    __shared__ __align__(16) _Float16 Ks[64 * 64];    // k fp16
    __shared__ __align__(16) _Float16 Vs[64 * 64];    // v fp16, [d][t]
    __shared__ __align__(16) _Float16 Ps[Pp * 64];    // p fp16, wave-private rows
    __shared__ __align__(16) float rtab[33 * 16 * 2];
    __shared__ int regs_s[64];
    __shared__ int starts_s[MAXN];

    for (int j = tid; j < 33 * 16 * 2; j += 512) rtab[j] = regtab[j];
    if (tid < MAXN) starts_s[tid] = starts[b * MAXN + tid];
    const float bs = bias_same[h];
    const float bd = bias_diff[h];
    __syncthreads();

    // ---- stage Q (rope, fp16) into persistent Qs ----
    const float* Qbh = q_in + (size_t)bh * Pp * Dd;
#pragma unroll
    for (int it = 0; it < 4; ++it) {
        int f  = tid + 512 * it;
        int p  = f >> 4;
        int dq = (f & 15) << 2;
        float4 x = ((const float4*)Qbh)[f];
        int fi = (dq & 31) >> 1;
        float4 cs;
        if (dq < 32) {
            int gpos = starts_s[p >> 2];
            cs = *(const float4*)(postab + (size_t)(gpos * 16 + fi) * 2);
        } else {
            int ridx = (p >> 2) + 1;
            cs = *(const float4*)(&rtab[(ridx * 16 + fi) * 2]);
        }
        f16x4 hh;
        hh[0] = (_Float16)(x.x * cs.x - x.y * cs.y);
        hh[1] = (_Float16)(x.x * cs.y + x.y * cs.x);
        hh[2] = (_Float16)(x.z * cs.z - x.w * cs.w);
        hh[3] = (_Float16)(x.z * cs.w + x.w * cs.z);
        *(f16x4*)(Qs + SW64(p, dq)) = hh;
    }
    __syncthreads();

    // ---- Q fragments from LDS (persistent source), 16 cols per wave ----
    f16x8 qh[2];
    {
        int pr = w * 16 + cl;
#pragma unroll
        for (int ks = 0; ks < 2; ++ks)
            qh[ks] = *(const f16x8*)(Qs + SW64(pr, ks * 32 + g * 8));
    }

    float m0 = -INFINITY, l0 = 0.f;
    f32x4 Oacc[4];
#pragma unroll
    for (int i1 = 0; i1 < 4; ++i1) Oacc[i1] = (f32x4)0.f;

    const float* Kbh = k_in + (size_t)bh * Tt * Dd;
    const float* Vbh = v_in + (size_t)bh * Tt * Dd;

    // ---- T14 prefetch state: next tile's raw data in registers (V packed fp16) ----
    float4 kx[2], kcs[2];
    int    krg[2], rreg;
    f16x8  vx16;
    auto prefetch = [&](int t0n) {
#pragma unroll
        for (int it = 0; it < 2; ++it) {
            int f   = tid + 512 * it;
            int row = f >> 4;
            int dq  = (f & 15) << 2;
            int fi  = (dq & 31) >> 1;
            kx[it]  = ((const float4*)(Kbh + (size_t)t0n * Dd))[f];
            kcs[it] = *(const float4*)(postab + (size_t)((t0n + row) * 16 + fi) * 2);
            krg[it] = regions[b * Tt + t0n + row];
        }
        {
            int dcol = tid & 63;
            int tl   = (tid >> 6) * 8;
#pragma unroll
            for (int r = 0; r < 8; ++r)
                vx16[r] = (_Float16)Vbh[(size_t)(t0n + tl + r) * Dd + dcol];
        }
        rreg = (tid < 64) ? regions[b * Tt + t0n + tid] : 0;
    };
    prefetch(c0);

    for (int tt = 0; tt < NTILE; ++tt) {
        const int t0 = c0 + tt * 64;
        __syncthreads();   // B1: previous tile fully consumed
        if (tid < 64) regs_s[tid] = rreg;

        // ---- convert prefetched K tile: rope fp16 -> LDS ----
#pragma unroll
        for (int it = 0; it < 2; ++it) {
            int f   = tid + 512 * it;
            int row = f >> 4;
            int dq  = (f & 15) << 2;
            float4 x = kx[it];
            float4 cs;
            if (dq < 32) {
                cs = kcs[it];
            } else {
                int rg = krg[it];
                cs = *(const float4*)(&rtab[(rg * 16 + ((dq & 31) >> 1)) * 2]);
            }
            f16x4 hh;
            hh[0] = (_Float16)(x.x * cs.x - x.y * cs.y);
            hh[1] = (_Float16)(x.x * cs.y + x.y * cs.x);
            hh[2] = (_Float16)(x.z * cs.z - x.w * cs.w);
            hh[3] = (_Float16)(x.z * cs.w + x.w * cs.z);
            *(f16x4*)(Ks + SW64(row, dq)) = hh;
        }

        // ---- write prefetched V tile (already fp16) -> LDS ----
        {
            int dcol = tid & 63;
            int tl   = (tid >> 6) * 8;
            *(f16x8*)(Vs + SW64(dcol, tl)) = vx16;
        }
        __syncthreads();   // B2: staging complete

        // ---- issue next tile's loads (latency hides under this tile's compute) ----
        if (tt + 1 < NTILE) prefetch(t0 + 64);

        // ---- QK^T MFMA, 2 k-steps (single fp16), setprio-wrapped ----
        f32x4 sacc[4];
#pragma unroll
        for (int mt = 0; mt < 4; ++mt) sacc[mt] = (f32x4)0.f;
        __builtin_amdgcn_s_setprio(1);
#pragma unroll
        for (int s = 0; s < 2; ++s) {
            f16x8 b0 = qh[s];
#pragma unroll
            for (int mt = 0; mt < 4; ++mt) {
                int tr = mt * 16 + cl;
                f16x8 ak = *(const f16x8*)(Ks + SW64(tr, s * 32 + g * 8));
                sacc[mt] = __builtin_amdgcn_mfma_f32_16x16x32_f16(ak, b0, sacc[mt], 0, 0, 0);
            }
        }
        __builtin_amdgcn_s_setprio(0);

        // ---- scale + bias; per-column (p) tile max ----
        float tmax0 = -INFINITY;
        const int ridx0 = ((w * 16 + cl) >> 2) + 1;
#pragma unroll
        for (int mt = 0; mt < 4; ++mt) {
#pragma unroll
            for (int r = 0; r < 4; ++r) {
                int rg = regs_s[mt * 16 + g * 4 + r];
                float s0 = sacc[mt][r] * 0.125f + ((ridx0 == rg) ? bs : bd);
                sacc[mt][r] = s0;
                tmax0 = fmaxf(tmax0, s0);
            }
        }
        tmax0 = fmaxf(tmax0, __shfl_xor(tmax0, 16, 64));
        tmax0 = fmaxf(tmax0, __shfl_xor(tmax0, 32, 64));
        float mn0 = fmaxf(m0, tmax0);
        float sc0 = __expf(m0 - mn0);

        // ---- P = exp(s - m_new) -> fp16 -> LDS (wave-private rows); f32 row sums ----
        float rs0 = 0.f;
#pragma unroll
        for (int mt = 0; mt < 4; ++mt) {
            f16x4 ph0;
#pragma unroll
            for (int r = 0; r < 4; ++r) {
                float e0 = __expf(sacc[mt][r] - mn0);
                rs0 += e0;
                ph0[r] = (_Float16)e0;
            }
            int trow = mt * 16 + g * 4;
            int pa = w * 16 + cl;
            *(f16x4*)(Ps + SW64(pa, trow)) = ph0;
        }
        rs0 += __shfl_xor(rs0, 16, 64); rs0 += __shfl_xor(rs0, 32, 64);
        l0 = l0 * sc0 + rs0; m0 = mn0;

        // P rows are wave-private: drain this wave's LDS writes, no block barrier
        asm volatile("s_waitcnt lgkmcnt(0)" ::: "memory");
        __builtin_amdgcn_sched_barrier(0);

        // ---- rescale O (factor per output row p = w*16 + g*4 + r) ----
#pragma unroll
        for (int r = 0; r < 4; ++r) {
            float f0 = __shfl(sc0, g * 4 + r, 64);
#pragma unroll
            for (int nt = 0; nt < 4; ++nt) Oacc[nt][r] *= f0;
        }

        // ---- PV: O += P·V (fp16, 2 k-steps), setprio-wrapped ----
        __builtin_amdgcn_s_setprio(1);
#pragma unroll
        for (int s = 0; s < 2; ++s) {
            f16x8 ap0;
            {
                int pp = w * 16 + cl;
                ap0 = *(const f16x8*)(Ps + SW64(pp, s * 32 + g * 8));
            }
#pragma unroll
            for (int nt = 0; nt < 4; ++nt) {
                int d = nt * 16 + cl;
                f16x8 bv = *(const f16x8*)(Vs + SW64(d, s * 32 + g * 8));
                Oacc[nt] = __builtin_amdgcn_mfma_f32_16x16x32_f16(ap0, bv, Oacc[nt], 0, 0, 0);
            }
        }
        __builtin_amdgcn_s_setprio(0);
    }

    // ---- write partials (fp16 pO; m,l stay f32) ----
    size_t obase = (size_t)(bh * NS + chunk) * Pp * Dd;
#pragma unroll
    for (int nt = 0; nt < 4; ++nt)
#pragma unroll
        for (int r = 0; r < 4; ++r) {
            int pb = w * 16 + g * 4 + r;
            int d  = nt * 16 + cl;
            pO[obase + pb * 64 + d] = (_Float16)Oacc[nt][r];
        }
    if (g == 0) {
        size_t mlb = (size_t)(bh * NS + chunk) * Pp;
        int p0 = w * 16 + cl;
        *(float2*)(pML + (mlb + p0) * 2) = make_float2(m0, l0);
    }
}

// ---------------- combine partials across T-chunks (vectorized f16x8 loads) ----------------
// grid = BHc*4 blocks, 256 threads. Thread t owns (p = pq*32 + (t>>3), d8 = (t&7)*8).
__global__ void k_combine(const _Float16* __restrict__ pO, const float* __restrict__ pML,
                          float* __restrict__ out, int NS) {
    int bh = blockIdx.x >> 2;
    int pq = blockIdx.x & 3;
    int p  = pq * 32 + (threadIdx.x >> 3);
    int d8 = (threadIdx.x & 7) * 8;

    float M = -INFINITY;
    float mv[8], lv[8];
    for (int c = 0; c < NS; ++c) {
        float2 ml = *(const float2*)(pML + ((size_t)(bh * NS + c) * Pp + p) * 2);
        mv[c] = ml.x; lv[c] = ml.y;
        M = fmaxf(M, ml.x);
    }
    float L = 0.f;
    float o[8];
#pragma unroll
    for (int j = 0; j < 8; ++j) o[j] = 0.f;
    for (int c = 0; c < NS; ++c) {
        float wgt = __expf(mv[c] - M);
        L += wgt * lv[c];
        f16x8 ov = *(const f16x8*)(pO + ((size_t)(bh * NS + c) * Pp + p) * Dd + d8);
#pragma unroll
        for (int j = 0; j < 8; ++j) o[j] += wgt * (float)ov[j];
    }
    float rL = 1.f / L;
    float4 o0 = make_float4(o[0] * rL, o[1] * rL, o[2] * rL, o[3] * rL);
    float4 o1 = make_float4(o[4] * rL, o[5] * rL, o[6] * rL, o[7] * rL);
    float* dst = out + ((size_t)bh * Pp + p) * Dd + d8;
    *(float4*)(dst + 0) = o0;
    *(float4*)(dst + 4) = o1;
}

// ---------------- launcher ----------------
extern "C" void kernel_launch(void* const* d_in, const int* in_sizes, int n_in,
                              void* d_out, int out_size, void* d_ws, size_t ws_size,
                              hipStream_t stream) {
    const float* q         = (const float*)d_in[0];
    const float* k         = (const float*)d_in[1];
    const float* v         = (const float*)d_in[2];
    const int*   regions   = (const int*)d_in[3];
    const float* bias_same = (const float*)d_in[7];
    const float* bias_diff = (const float*)d_in[8];

    float* ws     = (float*)d_ws;
    float* postab = ws;
    float* regtab = postab + Tt * 16 * 2;
    int*   starts = (int*)(regtab + 33 * 16 * 2);
    _Float16* pO  = (_Float16*)(starts + 128);
    size_t fixed_b = (size_t)((char*)pO - (char*)ws);

    int NS = 8;   // grid 512 = 2 blocks/CU resident (52.5 KB LDS)
    while (NS > 1 && fixed_b + (size_t)BHc * NS * Pp * (Dd * 2 + 8) > ws_size) NS >>= 1;
    float* pML = (float*)(pO + (size_t)BHc * NS * Pp * Dd);

    k_prelude<<<dim3(257), dim3(256), 0, stream>>>(regions, postab, regtab, starts);
    k_attn<<<dim3(BHc * NS), dim3(512), 0, stream>>>(q, k, v, regions, bias_same, bias_diff,
                                                     postab, regtab, starts, pO, pML, NS);
    k_combine<<<dim3(BHc * 4), dim3(256), 0, stream>>>(pO, pML, (float*)d_out, NS);
}

// Round 27
// 49.806 us; speedup vs baseline: 1.7149x; 1.1472x over previous
//
#include <hip/hip_runtime.h>
#include <hip/hip_bf16.h>
#include <math.h>

#define Bb   4
#define Hh   16
#define Tt   4096
#define Dd   64
#define Pp   128
#define MAXN 32
#define BHc  64   // B*H

typedef _Float16 f16x8 __attribute__((ext_vector_type(8)));
typedef _Float16 f16x4 __attribute__((ext_vector_type(4)));
typedef float    f32x4 __attribute__((ext_vector_type(4)));

// swizzled element index into a [row][64] fp16 LDS tile
#define SW64(row, col) (((row) * 64) + ((col) ^ (((row) & 7) << 3)))

// inv_freq in f32: 10000^(-fi/16) = exp2(-fi * log2(10000)/16)
__device__ __forceinline__ float inv_freq(int fi) {
    return exp2f(-(float)fi * 0.83048201f);
}

// ---------------- merged prelude: postab (blocks 0..255) + starts/regtab (block 256) ----------------
__global__ void k_prelude(const int* __restrict__ regions, float* __restrict__ postab,
                          float* __restrict__ regtab, int* __restrict__ starts) {
    int bidx = blockIdx.x;
    int tid  = threadIdx.x;
    if (bidx < 256) {
        int idx = bidx * 256 + tid;           // < 65536 = Tt*16
        int pos = idx >> 4, fi = idx & 15;
        float ang = (float)pos * inv_freq(fi);
        postab[idx * 2 + 0] = cosf(ang);
        postab[idx * 2 + 1] = sinf(ang);
        return;
    }
    // block 256: region starts (binary search on sorted regions) + regtab
    if (tid < Bb * MAXN) {
        int b = tid >> 5, n = (tid & 31) + 1;
        const int* r = regions + b * Tt;
        int lo = 0, hi = Tt;
        while (lo < hi) { int mid = (lo + hi) >> 1; if (r[mid] < n) lo = mid + 1; else hi = mid; }
        starts[tid] = (lo < Tt && r[lo] == n) ? lo : 0;
    }
    for (int j = tid; j < 33 * 16; j += 256) {
        int pos = j >> 4, fi = j & 15;
        float ang = (float)pos * inv_freq(fi);
        regtab[j * 2 + 0] = cosf(ang);
        regtab[j * 2 + 1] = sinf(ang);
    }
}

// ---------------- main kernel: r26 structure, kcs NOT prefetched (read postab at convert) ----------------
__global__ __launch_bounds__(512) void k_attn(
    const float* __restrict__ q_in, const float* __restrict__ k_in,
    const float* __restrict__ v_in, const int* __restrict__ regions,
    const float* __restrict__ bias_same, const float* __restrict__ bias_diff,
    const float* __restrict__ postab, const float* __restrict__ regtab,
    const int* __restrict__ starts, _Float16* __restrict__ pO,
    float* __restrict__ pML, int NS)
{
    const int bid   = blockIdx.x;
    const int chunk = bid % NS;
    const int bh    = bid / NS;
    const int b     = bh >> 4;
    const int h     = bh & 15;
    const int C     = Tt / NS;
    const int NTILE = C >> 6;
    const int c0    = chunk * C;

    const int tid = threadIdx.x;
    const int w  = tid >> 6;        // wave 0..7, owns p cols [16w, 16w+16)
    const int l  = tid & 63;
    const int cl = l & 15;
    const int g  = l >> 4;

    __shared__ __align__(16) _Float16 Qs[Pp * 64];    // q fp16, PERSISTENT
    __shared__ __align__(16) _Float16 Ks[64 * 64];    // k fp16
    __shared__ __align__(16) _Float16 Vs[64 * 64];    // v fp16, [d][t]
    __shared__ __align__(16) _Float16 Ps[Pp * 64];    // p fp16, wave-private rows
    __shared__ __align__(16) float rtab[33 * 16 * 2];
    __shared__ int regs_s[64];
    __shared__ int starts_s[MAXN];

    for (int j = tid; j < 33 * 16 * 2; j += 512) rtab[j] = regtab[j];
    if (tid < MAXN) starts_s[tid] = starts[b * MAXN + tid];
    const float bs = bias_same[h];
    const float bd = bias_diff[h];
    __syncthreads();

    // ---- stage Q (rope, fp16) into persistent Qs ----
    const float* Qbh = q_in + (size_t)bh * Pp * Dd;
#pragma unroll
    for (int it = 0; it < 4; ++it) {
        int f  = tid + 512 * it;
        int p  = f >> 4;
        int dq = (f & 15) << 2;
        float4 x = ((const float4*)Qbh)[f];
        int fi = (dq & 31) >> 1;
        float4 cs;
        if (dq < 32) {
            int gpos = starts_s[p >> 2];
            cs = *(const float4*)(postab + (size_t)(gpos * 16 + fi) * 2);
        } else {
            int ridx = (p >> 2) + 1;
            cs = *(const float4*)(&rtab[(ridx * 16 + fi) * 2]);
        }
        f16x4 hh;
        hh[0] = (_Float16)(x.x * cs.x - x.y * cs.y);
        hh[1] = (_Float16)(x.x * cs.y + x.y * cs.x);
        hh[2] = (_Float16)(x.z * cs.z - x.w * cs.w);
        hh[3] = (_Float16)(x.z * cs.w + x.w * cs.z);
        *(f16x4*)(Qs + SW64(p, dq)) = hh;
    }
    __syncthreads();

    // ---- Q fragments from LDS (persistent source), 16 cols per wave ----
    f16x8 qh[2];
    {
        int pr = w * 16 + cl;
#pragma unroll
        for (int ks = 0; ks < 2; ++ks)
            qh[ks] = *(const f16x8*)(Qs + SW64(pr, ks * 32 + g * 8));
    }

    float m0 = -INFINITY, l0 = 0.f;
    f32x4 Oacc[4];
#pragma unroll
    for (int i1 = 0; i1 < 4; ++i1) Oacc[i1] = (f32x4)0.f;

    const float* Kbh = k_in + (size_t)bh * Tt * Dd;
    const float* Vbh = v_in + (size_t)bh * Tt * Dd;

    // ---- prefetch state: K raw data + region ids + V (fp16-packed); NO kcs ----
    float4 kx[2];
    int    krg[2], rreg;
    f16x8  vx16;
    auto prefetch = [&](int t0n) {
#pragma unroll
        for (int it = 0; it < 2; ++it) {
            int f   = tid + 512 * it;
            int row = f >> 4;
            kx[it]  = ((const float4*)(Kbh + (size_t)t0n * Dd))[f];
            krg[it] = regions[b * Tt + t0n + row];
        }
        {
            int dcol = tid & 63;
            int tl   = (tid >> 6) * 8;
#pragma unroll
            for (int r = 0; r < 8; ++r)
                vx16[r] = (_Float16)Vbh[(size_t)(t0n + tl + r) * Dd + dcol];
        }
        rreg = (tid < 64) ? regions[b * Tt + t0n + tid] : 0;
    };
    prefetch(c0);

    for (int tt = 0; tt < NTILE; ++tt) {
        const int t0 = c0 + tt * 64;
        __syncthreads();   // B1: previous tile fully consumed
        if (tid < 64) regs_s[tid] = rreg;

        // ---- convert prefetched K tile: rope fp16 -> LDS (cos/sin read here, L2-hot) ----
#pragma unroll
        for (int it = 0; it < 2; ++it) {
            int f   = tid + 512 * it;
            int row = f >> 4;
            int dq  = (f & 15) << 2;
            int fi  = (dq & 31) >> 1;
            float4 x = kx[it];
            float4 cs;
            if (dq < 32) {
                cs = *(const float4*)(postab + (size_t)((t0 + row) * 16 + fi) * 2);
            } else {
                int rg = krg[it];
                cs = *(const float4*)(&rtab[(rg * 16 + fi) * 2]);
            }
            f16x4 hh;
            hh[0] = (_Float16)(x.x * cs.x - x.y * cs.y);
            hh[1] = (_Float16)(x.x * cs.y + x.y * cs.x);
            hh[2] = (_Float16)(x.z * cs.z - x.w * cs.w);
            hh[3] = (_Float16)(x.z * cs.w + x.w * cs.z);
            *(f16x4*)(Ks + SW64(row, dq)) = hh;
        }

        // ---- write prefetched V tile (already fp16) -> LDS ----
        {
            int dcol = tid & 63;
            int tl   = (tid >> 6) * 8;
            *(f16x8*)(Vs + SW64(dcol, tl)) = vx16;
        }
        __syncthreads();   // B2: staging complete

        // ---- issue next tile's loads (latency hides under this tile's compute) ----
        if (tt + 1 < NTILE) prefetch(t0 + 64);

        // ---- QK^T MFMA, 2 k-steps (single fp16), setprio-wrapped ----
        f32x4 sacc[4];
#pragma unroll
        for (int mt = 0; mt < 4; ++mt) sacc[mt] = (f32x4)0.f;
        __builtin_amdgcn_s_setprio(1);
#pragma unroll
        for (int s = 0; s < 2; ++s) {
            f16x8 b0 = qh[s];
#pragma unroll
            for (int mt = 0; mt < 4; ++mt) {
                int tr = mt * 16 + cl;
                f16x8 ak = *(const f16x8*)(Ks + SW64(tr, s * 32 + g * 8));
                sacc[mt] = __builtin_amdgcn_mfma_f32_16x16x32_f16(ak, b0, sacc[mt], 0, 0, 0);
            }
        }
        __builtin_amdgcn_s_setprio(0);

        // ---- scale + bias; per-column (p) tile max ----
        float tmax0 = -INFINITY;
        const int ridx0 = ((w * 16 + cl) >> 2) + 1;
#pragma unroll
        for (int mt = 0; mt < 4; ++mt) {
#pragma unroll
            for (int r = 0; r < 4; ++r) {
                int rg = regs_s[mt * 16 + g * 4 + r];
                float s0 = sacc[mt][r] * 0.125f + ((ridx0 == rg) ? bs : bd);
                sacc[mt][r] = s0;
                tmax0 = fmaxf(tmax0, s0);
            }
        }
        tmax0 = fmaxf(tmax0, __shfl_xor(tmax0, 16, 64));
        tmax0 = fmaxf(tmax0, __shfl_xor(tmax0, 32, 64));
        float mn0 = fmaxf(m0, tmax0);
        float sc0 = __expf(m0 - mn0);

        // ---- P = exp(s - m_new) -> fp16 -> LDS (wave-private rows); f32 row sums ----
        float rs0 = 0.f;
#pragma unroll
        for (int mt = 0; mt < 4; ++mt) {
            f16x4 ph0;
#pragma unroll
            for (int r = 0; r < 4; ++r) {
                float e0 = __expf(sacc[mt][r] - mn0);
                rs0 += e0;
                ph0[r] = (_Float16)e0;
            }
            int trow = mt * 16 + g * 4;
            int pa = w * 16 + cl;
            *(f16x4*)(Ps + SW64(pa, trow)) = ph0;
        }
        rs0 += __shfl_xor(rs0, 16, 64); rs0 += __shfl_xor(rs0, 32, 64);
        l0 = l0 * sc0 + rs0; m0 = mn0;

        // P rows are wave-private: drain this wave's LDS writes, no block barrier
        asm volatile("s_waitcnt lgkmcnt(0)" ::: "memory");
        __builtin_amdgcn_sched_barrier(0);

        // ---- rescale O (factor per output row p = w*16 + g*4 + r) ----
#pragma unroll
        for (int r = 0; r < 4; ++r) {
            float f0 = __shfl(sc0, g * 4 + r, 64);
#pragma unroll
            for (int nt = 0; nt < 4; ++nt) Oacc[nt][r] *= f0;
        }

        // ---- PV: O += P·V (fp16, 2 k-steps), setprio-wrapped ----
        __builtin_amdgcn_s_setprio(1);
#pragma unroll
        for (int s = 0; s < 2; ++s) {
            f16x8 ap0;
            {
                int pp = w * 16 + cl;
                ap0 = *(const f16x8*)(Ps + SW64(pp, s * 32 + g * 8));
            }
#pragma unroll
            for (int nt = 0; nt < 4; ++nt) {
                int d = nt * 16 + cl;
                f16x8 bv = *(const f16x8*)(Vs + SW64(d, s * 32 + g * 8));
                Oacc[nt] = __builtin_amdgcn_mfma_f32_16x16x32_f16(ap0, bv, Oacc[nt], 0, 0, 0);
            }
        }
        __builtin_amdgcn_s_setprio(0);
    }

    // ---- write partials (fp16 pO; m,l stay f32) ----
    size_t obase = (size_t)(bh * NS + chunk) * Pp * Dd;
#pragma unroll
    for (int nt = 0; nt < 4; ++nt)
#pragma unroll
        for (int r = 0; r < 4; ++r) {
            int pb = w * 16 + g * 4 + r;
            int d  = nt * 16 + cl;
            pO[obase + pb * 64 + d] = (_Float16)Oacc[nt][r];
        }
    if (g == 0) {
        size_t mlb = (size_t)(bh * NS + chunk) * Pp;
        int p0 = w * 16 + cl;
        *(float2*)(pML + (mlb + p0) * 2) = make_float2(m0, l0);
    }
}

// ---------------- combine partials across T-chunks (vectorized f16x8 loads) ----------------
__global__ void k_combine(const _Float16* __restrict__ pO, const float* __restrict__ pML,
                          float* __restrict__ out, int NS) {
    int bh = blockIdx.x >> 2;
    int pq = blockIdx.x & 3;
    int p  = pq * 32 + (threadIdx.x >> 3);
    int d8 = (threadIdx.x & 7) * 8;

    float M = -INFINITY;
    float mv[8], lv[8];
    for (int c = 0; c < NS; ++c) {
        float2 ml = *(const float2*)(pML + ((size_t)(bh * NS + c) * Pp + p) * 2);
        mv[c] = ml.x; lv[c] = ml.y;
        M = fmaxf(M, ml.x);
    }
    float L = 0.f;
    float o[8];
#pragma unroll
    for (int j = 0; j < 8; ++j) o[j] = 0.f;
    for (int c = 0; c < NS; ++c) {
        float wgt = __expf(mv[c] - M);
        L += wgt * lv[c];
        f16x8 ov = *(const f16x8*)(pO + ((size_t)(bh * NS + c) * Pp + p) * Dd + d8);
#pragma unroll
        for (int j = 0; j < 8; ++j) o[j] += wgt * (float)ov[j];
    }
    float rL = 1.f / L;
    float4 o0 = make_float4(o[0] * rL, o[1] * rL, o[2] * rL, o[3] * rL);
    float4 o1 = make_float4(o[4] * rL, o[5] * rL, o[6] * rL, o[7] * rL);
    float* dst = out + ((size_t)bh * Pp + p) * Dd + d8;
    *(float4*)(dst + 0) = o0;
    *(float4*)(dst + 4) = o1;
}

// ---------------- launcher ----------------
extern "C" void kernel_launch(void* const* d_in, const int* in_sizes, int n_in,
                              void* d_out, int out_size, void* d_ws, size_t ws_size,
                              hipStream_t stream) {
    const float* q         = (const float*)d_in[0];
    const float* k         = (const float*)d_in[1];
    const float* v         = (const float*)d_in[2];
    const int*   regions   = (const int*)d_in[3];
    const float* bias_same = (const float*)d_in[7];
    const float* bias_diff = (const float*)d_in[8];

    float* ws     = (float*)d_ws;
    float* postab = ws;
    float* regtab = postab + Tt * 16 * 2;
    int*   starts = (int*)(regtab + 33 * 16 * 2);
    _Float16* pO  = (_Float16*)(starts + 128);
    size_t fixed_b = (size_t)((char*)pO - (char*)ws);

    int NS = 8;   // grid 512 = 2 blocks/CU resident (52.5 KB LDS)
    while (NS > 1 && fixed_b + (size_t)BHc * NS * Pp * (Dd * 2 + 8) > ws_size) NS >>= 1;
    float* pML = (float*)(pO + (size_t)BHc * NS * Pp * Dd);

    k_prelude<<<dim3(257), dim3(256), 0, stream>>>(regions, postab, regtab, starts);
    k_attn<<<dim3(BHc * NS), dim3(512), 0, stream>>>(q, k, v, regions, bias_same, bias_diff,
                                                     postab, regtab, starts, pO, pML, NS);
    k_combine<<<dim3(BHc * 4), dim3(256), 0, stream>>>(pO, pML, (float*)d_out, NS);
}

// Round 28
// 49.436 us; speedup vs baseline: 1.7277x; 1.0075x over previous
//
#include <hip/hip_runtime.h>
#include <hip/hip_bf16.h>
#include <math.h>

#define Bb   4
#define Hh   16
#define Tt   4096
#define Dd   64
#define Pp   128
#define MAXN 32
#define BHc  64   // B*H

typedef _Float16 f16x8 __attribute__((ext_vector_type(8)));
typedef _Float16 f16x4 __attribute__((ext_vector_type(4)));
typedef float    f32x4 __attribute__((ext_vector_type(4)));

// swizzled element index into a [row][64] fp16 LDS tile
#define SW64(row, col) (((row) * 64) + ((col) ^ (((row) & 7) << 3)))

// inv_freq in f32: 10000^(-fi/16) = exp2(-fi * log2(10000)/16)
__device__ __forceinline__ float inv_freq(int fi) {
    return exp2f(-(float)fi * 0.83048201f);
}

// ---------------- merged prelude: postab (blocks 0..255) + starts/regtab (block 256) ----------------
__global__ void k_prelude(const int* __restrict__ regions, float* __restrict__ postab,
                          float* __restrict__ regtab, int* __restrict__ starts) {
    int bidx = blockIdx.x;
    int tid  = threadIdx.x;
    if (bidx < 256) {
        int idx = bidx * 256 + tid;           // < 65536 = Tt*16
        int pos = idx >> 4, fi = idx & 15;
        float ang = (float)pos * inv_freq(fi);
        postab[idx * 2 + 0] = cosf(ang);
        postab[idx * 2 + 1] = sinf(ang);
        return;
    }
    // block 256: region starts (binary search on sorted regions) + regtab
    if (tid < Bb * MAXN) {
        int b = tid >> 5, n = (tid & 31) + 1;
        const int* r = regions + b * Tt;
        int lo = 0, hi = Tt;
        while (lo < hi) { int mid = (lo + hi) >> 1; if (r[mid] < n) lo = mid + 1; else hi = mid; }
        starts[tid] = (lo < Tt && r[lo] == n) ? lo : 0;
    }
    for (int j = tid; j < 33 * 16; j += 256) {
        int pos = j >> 4, fi = j & 15;
        float ang = (float)pos * inv_freq(fi);
        regtab[j * 2 + 0] = cosf(ang);
        regtab[j * 2 + 1] = sinf(ang);
    }
}

// ---------------- main kernel: r27 + fp16 kcs prefetch (4 VGPR, hides postab L2 latency) ----------------
__global__ __launch_bounds__(512) void k_attn(
    const float* __restrict__ q_in, const float* __restrict__ k_in,
    const float* __restrict__ v_in, const int* __restrict__ regions,
    const float* __restrict__ bias_same, const float* __restrict__ bias_diff,
    const float* __restrict__ postab, const float* __restrict__ regtab,
    const int* __restrict__ starts, _Float16* __restrict__ pO,
    float* __restrict__ pML, int NS)
{
    const int bid   = blockIdx.x;
    const int chunk = bid % NS;
    const int bh    = bid / NS;
    const int b     = bh >> 4;
    const int h     = bh & 15;
    const int C     = Tt / NS;
    const int NTILE = C >> 6;
    const int c0    = chunk * C;

    const int tid = threadIdx.x;
    const int w  = tid >> 6;        // wave 0..7, owns p cols [16w, 16w+16)
    const int l  = tid & 63;
    const int cl = l & 15;
    const int g  = l >> 4;

    __shared__ __align__(16) _Float16 Qs[Pp * 64];    // q fp16, PERSISTENT
    __shared__ __align__(16) _Float16 Ks[64 * 64];    // k fp16
    __shared__ __align__(16) _Float16 Vs[64 * 64];    // v fp16, [d][t]
    __shared__ __align__(16) _Float16 Ps[Pp * 64];    // p fp16, wave-private rows
    __shared__ __align__(16) float rtab[33 * 16 * 2];
    __shared__ int regs_s[64];
    __shared__ int starts_s[MAXN];

    for (int j = tid; j < 33 * 16 * 2; j += 512) rtab[j] = regtab[j];
    if (tid < MAXN) starts_s[tid] = starts[b * MAXN + tid];
    const float bs = bias_same[h];
    const float bd = bias_diff[h];
    __syncthreads();

    // ---- stage Q (rope, fp16) into persistent Qs ----
    const float* Qbh = q_in + (size_t)bh * Pp * Dd;
#pragma unroll
    for (int it = 0; it < 4; ++it) {
        int f  = tid + 512 * it;
        int p  = f >> 4;
        int dq = (f & 15) << 2;
        float4 x = ((const float4*)Qbh)[f];
        int fi = (dq & 31) >> 1;
        float4 cs;
        if (dq < 32) {
            int gpos = starts_s[p >> 2];
            cs = *(const float4*)(postab + (size_t)(gpos * 16 + fi) * 2);
        } else {
            int ridx = (p >> 2) + 1;
            cs = *(const float4*)(&rtab[(ridx * 16 + fi) * 2]);
        }
        f16x4 hh;
        hh[0] = (_Float16)(x.x * cs.x - x.y * cs.y);
        hh[1] = (_Float16)(x.x * cs.y + x.y * cs.x);
        hh[2] = (_Float16)(x.z * cs.z - x.w * cs.w);
        hh[3] = (_Float16)(x.z * cs.w + x.w * cs.z);
        *(f16x4*)(Qs + SW64(p, dq)) = hh;
    }
    __syncthreads();

    // ---- Q fragments from LDS (persistent source), 16 cols per wave ----
    f16x8 qh[2];
    {
        int pr = w * 16 + cl;
#pragma unroll
        for (int ks = 0; ks < 2; ++ks)
            qh[ks] = *(const f16x8*)(Qs + SW64(pr, ks * 32 + g * 8));
    }

    float m0 = -INFINITY, l0 = 0.f;
    f32x4 Oacc[4];
#pragma unroll
    for (int i1 = 0; i1 < 4; ++i1) Oacc[i1] = (f32x4)0.f;

    const float* Kbh = k_in + (size_t)bh * Tt * Dd;
    const float* Vbh = v_in + (size_t)bh * Tt * Dd;

    // ---- prefetch state: K raw f32 + cos/sin fp16 + region ids + V fp16 ----
    float4 kx[2];
    f16x4  kcs16[2];
    int    krg[2], rreg;
    f16x8  vx16;
    auto prefetch = [&](int t0n) {
#pragma unroll
        for (int it = 0; it < 2; ++it) {
            int f   = tid + 512 * it;
            int row = f >> 4;
            int dq  = (f & 15) << 2;
            int fi  = (dq & 31) >> 1;
            kx[it]  = ((const float4*)(Kbh + (size_t)t0n * Dd))[f];
            float4 c = *(const float4*)(postab + (size_t)((t0n + row) * 16 + fi) * 2);
            f16x4 cc;
            cc[0] = (_Float16)c.x; cc[1] = (_Float16)c.y;
            cc[2] = (_Float16)c.z; cc[3] = (_Float16)c.w;
            kcs16[it] = cc;
            krg[it] = regions[b * Tt + t0n + row];
        }
        {
            int dcol = tid & 63;
            int tl   = (tid >> 6) * 8;
#pragma unroll
            for (int r = 0; r < 8; ++r)
                vx16[r] = (_Float16)Vbh[(size_t)(t0n + tl + r) * Dd + dcol];
        }
        rreg = (tid < 64) ? regions[b * Tt + t0n + tid] : 0;
    };
    prefetch(c0);

    for (int tt = 0; tt < NTILE; ++tt) {
        const int t0 = c0 + tt * 64;
        __syncthreads();   // B1: previous tile fully consumed
        if (tid < 64) regs_s[tid] = rreg;

        // ---- convert prefetched K tile: rope fp16 -> LDS (cos/sin from fp16 regs) ----
#pragma unroll
        for (int it = 0; it < 2; ++it) {
            int f   = tid + 512 * it;
            int row = f >> 4;
            int dq  = (f & 15) << 2;
            float4 x = kx[it];
            float4 cs;
            if (dq < 32) {
                f16x4 cc = kcs16[it];
                cs = make_float4((float)cc[0], (float)cc[1], (float)cc[2], (float)cc[3]);
            } else {
                int rg = krg[it];
                cs = *(const float4*)(&rtab[(rg * 16 + ((dq & 31) >> 1)) * 2]);
            }
            f16x4 hh;
            hh[0] = (_Float16)(x.x * cs.x - x.y * cs.y);
            hh[1] = (_Float16)(x.x * cs.y + x.y * cs.x);
            hh[2] = (_Float16)(x.z * cs.z - x.w * cs.w);
            hh[3] = (_Float16)(x.z * cs.w + x.w * cs.z);
            *(f16x4*)(Ks + SW64(row, dq)) = hh;
        }

        // ---- write prefetched V tile (already fp16) -> LDS ----
        {
            int dcol = tid & 63;
            int tl   = (tid >> 6) * 8;
            *(f16x8*)(Vs + SW64(dcol, tl)) = vx16;
        }
        __syncthreads();   // B2: staging complete

        // ---- issue next tile's loads (latency hides under this tile's compute) ----
        if (tt + 1 < NTILE) prefetch(t0 + 64);

        // ---- QK^T MFMA, 2 k-steps (single fp16), setprio-wrapped ----
        f32x4 sacc[4];
#pragma unroll
        for (int mt = 0; mt < 4; ++mt) sacc[mt] = (f32x4)0.f;
        __builtin_amdgcn_s_setprio(1);
#pragma unroll
        for (int s = 0; s < 2; ++s) {
            f16x8 b0 = qh[s];
#pragma unroll
            for (int mt = 0; mt < 4; ++mt) {
                int tr = mt * 16 + cl;
                f16x8 ak = *(const f16x8*)(Ks + SW64(tr, s * 32 + g * 8));
                sacc[mt] = __builtin_amdgcn_mfma_f32_16x16x32_f16(ak, b0, sacc[mt], 0, 0, 0);
            }
        }
        __builtin_amdgcn_s_setprio(0);

        // ---- scale + bias; per-column (p) tile max ----
        float tmax0 = -INFINITY;
        const int ridx0 = ((w * 16 + cl) >> 2) + 1;
#pragma unroll
        for (int mt = 0; mt < 4; ++mt) {
#pragma unroll
            for (int r = 0; r < 4; ++r) {
                int rg = regs_s[mt * 16 + g * 4 + r];
                float s0 = sacc[mt][r] * 0.125f + ((ridx0 == rg) ? bs : bd);
                sacc[mt][r] = s0;
                tmax0 = fmaxf(tmax0, s0);
            }
        }
        tmax0 = fmaxf(tmax0, __shfl_xor(tmax0, 16, 64));
        tmax0 = fmaxf(tmax0, __shfl_xor(tmax0, 32, 64));
        float mn0 = fmaxf(m0, tmax0);
        float sc0 = __expf(m0 - mn0);

        // ---- P = exp(s - m_new) -> fp16 -> LDS (wave-private rows); f32 row sums ----
        float rs0 = 0.f;
#pragma unroll
        for (int mt = 0; mt < 4; ++mt) {
            f16x4 ph0;
#pragma unroll
            for (int r = 0; r < 4; ++r) {
                float e0 = __expf(sacc[mt][r] - mn0);
                rs0 += e0;
                ph0[r] = (_Float16)e0;
            }
            int trow = mt * 16 + g * 4;
            int pa = w * 16 + cl;
            *(f16x4*)(Ps + SW64(pa, trow)) = ph0;
        }
        rs0 += __shfl_xor(rs0, 16, 64); rs0 += __shfl_xor(rs0, 32, 64);
        l0 = l0 * sc0 + rs0; m0 = mn0;

        // P rows are wave-private: drain this wave's LDS writes, no block barrier
        asm volatile("s_waitcnt lgkmcnt(0)" ::: "memory");
        __builtin_amdgcn_sched_barrier(0);

        // ---- rescale O (factor per output row p = w*16 + g*4 + r) ----
#pragma unroll
        for (int r = 0; r < 4; ++r) {
            float f0 = __shfl(sc0, g * 4 + r, 64);
#pragma unroll
            for (int nt = 0; nt < 4; ++nt) Oacc[nt][r] *= f0;
        }

        // ---- PV: O += P·V (fp16, 2 k-steps), setprio-wrapped ----
        __builtin_amdgcn_s_setprio(1);
#pragma unroll
        for (int s = 0; s < 2; ++s) {
            f16x8 ap0;
            {
                int pp = w * 16 + cl;
                ap0 = *(const f16x8*)(Ps + SW64(pp, s * 32 + g * 8));
            }
#pragma unroll
            for (int nt = 0; nt < 4; ++nt) {
                int d = nt * 16 + cl;
                f16x8 bv = *(const f16x8*)(Vs + SW64(d, s * 32 + g * 8));
                Oacc[nt] = __builtin_amdgcn_mfma_f32_16x16x32_f16(ap0, bv, Oacc[nt], 0, 0, 0);
            }
        }
        __builtin_amdgcn_s_setprio(0);
    }

    // ---- write partials (fp16 pO; m,l stay f32) ----
    size_t obase = (size_t)(bh * NS + chunk) * Pp * Dd;
#pragma unroll
    for (int nt = 0; nt < 4; ++nt)
#pragma unroll
        for (int r = 0; r < 4; ++r) {
            int pb = w * 16 + g * 4 + r;
            int d  = nt * 16 + cl;
            pO[obase + pb * 64 + d] = (_Float16)Oacc[nt][r];
        }
    if (g == 0) {
        size_t mlb = (size_t)(bh * NS + chunk) * Pp;
        int p0 = w * 16 + cl;
        *(float2*)(pML + (mlb + p0) * 2) = make_float2(m0, l0);
    }
}

// ---------------- combine partials across T-chunks (vectorized f16x8 loads) ----------------
__global__ void k_combine(const _Float16* __restrict__ pO, const float* __restrict__ pML,
                          float* __restrict__ out, int NS) {
    int bh = blockIdx.x >> 2;
    int pq = blockIdx.x & 3;
    int p  = pq * 32 + (threadIdx.x >> 3);
    int d8 = (threadIdx.x & 7) * 8;

    float M = -INFINITY;
    float mv[8], lv[8];
    for (int c = 0; c < NS; ++c) {
        float2 ml = *(const float2*)(pML + ((size_t)(bh * NS + c) * Pp + p) * 2);
        mv[c] = ml.x; lv[c] = ml.y;
        M = fmaxf(M, ml.x);
    }
    float L = 0.f;
    float o[8];
#pragma unroll
    for (int j = 0; j < 8; ++j) o[j] = 0.f;
    for (int c = 0; c < NS; ++c) {
        float wgt = __expf(mv[c] - M);
        L += wgt * lv[c];
        f16x8 ov = *(const f16x8*)(pO + ((size_t)(bh * NS + c) * Pp + p) * Dd + d8);
#pragma unroll
        for (int j = 0; j < 8; ++j) o[j] += wgt * (float)ov[j];
    }
    float rL = 1.f / L;
    float4 o0 = make_float4(o[0] * rL, o[1] * rL, o[2] * rL, o[3] * rL);
    float4 o1 = make_float4(o[4] * rL, o[5] * rL, o[6] * rL, o[7] * rL);
    float* dst = out + ((size_t)bh * Pp + p) * Dd + d8;
    *(float4*)(dst + 0) = o0;
    *(float4*)(dst + 4) = o1;
}

// ---------------- launcher ----------------
extern "C" void kernel_launch(void* const* d_in, const int* in_sizes, int n_in,
                              void* d_out, int out_size, void* d_ws, size_t ws_size,
                              hipStream_t stream) {
    const float* q         = (const float*)d_in[0];
    const float* k         = (const float*)d_in[1];
    const float* v         = (const float*)d_in[2];
    const int*   regions   = (const int*)d_in[3];
    const float* bias_same = (const float*)d_in[7];
    const float* bias_diff = (const float*)d_in[8];

    float* ws     = (float*)d_ws;
    float* postab = ws;
    float* regtab = postab + Tt * 16 * 2;
    int*   starts = (int*)(regtab + 33 * 16 * 2);
    _Float16* pO  = (_Float16*)(starts + 128);
    size_t fixed_b = (size_t)((char*)pO - (char*)ws);

    int NS = 8;   // grid 512 = 2 blocks/CU resident (52.5 KB LDS)
    while (NS > 1 && fixed_b + (size_t)BHc * NS * Pp * (Dd * 2 + 8) > ws_size) NS >>= 1;
    float* pML = (float*)(pO + (size_t)BHc * NS * Pp * Dd);

    k_prelude<<<dim3(257), dim3(256), 0, stream>>>(regions, postab, regtab, starts);
    k_attn<<<dim3(BHc * NS), dim3(512), 0, stream>>>(q, k, v, regions, bias_same, bias_diff,
                                                     postab, regtab, starts, pO, pML, NS);
    k_combine<<<dim3(BHc * 4), dim3(256), 0, stream>>>(pO, pML, (float*)d_out, NS);
}

// Round 30
// 49.146 us; speedup vs baseline: 1.7380x; 1.0059x over previous
//
#include <hip/hip_runtime.h>
#include <hip/hip_bf16.h>
#include <math.h>

#define Bb   4
#define Hh   16
#define Tt   4096
#define Dd   64
#define Pp   128
#define MAXN 32
#define BHc  64   // B*H

typedef _Float16 f16x8 __attribute__((ext_vector_type(8)));
typedef _Float16 f16x4 __attribute__((ext_vector_type(4)));
typedef float    f32x4 __attribute__((ext_vector_type(4)));

// swizzled element index into a [row][64] fp16 LDS tile
#define SW64(row, col) (((row) * 64) + ((col) ^ (((row) & 7) << 3)))

// inv_freq in f32: 10000^(-fi/16) = exp2(-fi * log2(10000)/16)
__device__ __forceinline__ float inv_freq(int fi) {
    return exp2f(-(float)fi * 0.83048201f);
}

// ---------------- merged prelude: postab (blocks 0..255) + starts/regtab (block 256) ----------------
__global__ void k_prelude(const int* __restrict__ regions, float* __restrict__ postab,
                          float* __restrict__ regtab, int* __restrict__ starts) {
    int bidx = blockIdx.x;
    int tid  = threadIdx.x;
    if (bidx < 256) {
        int idx = bidx * 256 + tid;           // < 65536 = Tt*16
        int pos = idx >> 4, fi = idx & 15;
        float ang = (float)pos * inv_freq(fi);
        postab[idx * 2 + 0] = cosf(ang);
        postab[idx * 2 + 1] = sinf(ang);
        return;
    }
    // block 256: region starts (binary search on sorted regions) + regtab
    if (tid < Bb * MAXN) {
        int b = tid >> 5, n = (tid & 31) + 1;
        const int* r = regions + b * Tt;
        int lo = 0, hi = Tt;
        while (lo < hi) { int mid = (lo + hi) >> 1; if (r[mid] < n) lo = mid + 1; else hi = mid; }
        starts[tid] = (lo < Tt && r[lo] == n) ? lo : 0;
    }
    for (int j = tid; j < 33 * 16; j += 256) {
        int pos = j >> 4, fi = j & 15;
        float ang = (float)pos * inv_freq(fi);
        regtab[j * 2 + 0] = cosf(ang);
        regtab[j * 2 + 1] = sinf(ang);
    }
}

// ---------------- main kernel: r28 (best verified: 49.4 us, absmax 4.88e-4) ----------------
__global__ __launch_bounds__(512) void k_attn(
    const float* __restrict__ q_in, const float* __restrict__ k_in,
    const float* __restrict__ v_in, const int* __restrict__ regions,
    const float* __restrict__ bias_same, const float* __restrict__ bias_diff,
    const float* __restrict__ postab, const float* __restrict__ regtab,
    const int* __restrict__ starts, _Float16* __restrict__ pO,
    float* __restrict__ pML, int NS)
{
    const int bid   = blockIdx.x;
    const int chunk = bid % NS;
    const int bh    = bid / NS;
    const int b     = bh >> 4;
    const int h     = bh & 15;
    const int C     = Tt / NS;
    const int NTILE = C >> 6;
    const int c0    = chunk * C;

    const int tid = threadIdx.x;
    const int w  = tid >> 6;        // wave 0..7, owns p cols [16w, 16w+16)
    const int l  = tid & 63;
    const int cl = l & 15;
    const int g  = l >> 4;

    __shared__ __align__(16) _Float16 Qs[Pp * 64];    // q fp16, PERSISTENT
    __shared__ __align__(16) _Float16 Ks[64 * 64];    // k fp16
    __shared__ __align__(16) _Float16 Vs[64 * 64];    // v fp16, [d][t]
    __shared__ __align__(16) _Float16 Ps[Pp * 64];    // p fp16, wave-private rows
    __shared__ __align__(16) float rtab[33 * 16 * 2];
    __shared__ int regs_s[64];
    __shared__ int starts_s[MAXN];

    for (int j = tid; j < 33 * 16 * 2; j += 512) rtab[j] = regtab[j];
    if (tid < MAXN) starts_s[tid] = starts[b * MAXN + tid];
    const float bs = bias_same[h];
    const float bd = bias_diff[h];
    __syncthreads();

    // ---- stage Q (rope, fp16) into persistent Qs ----
    const float* Qbh = q_in + (size_t)bh * Pp * Dd;
#pragma unroll
    for (int it = 0; it < 4; ++it) {
        int f  = tid + 512 * it;
        int p  = f >> 4;
        int dq = (f & 15) << 2;
        float4 x = ((const float4*)Qbh)[f];
        int fi = (dq & 31) >> 1;
        float4 cs;
        if (dq < 32) {
            int gpos = starts_s[p >> 2];
            cs = *(const float4*)(postab + (size_t)(gpos * 16 + fi) * 2);
        } else {
            int ridx = (p >> 2) + 1;
            cs = *(const float4*)(&rtab[(ridx * 16 + fi) * 2]);
        }
        f16x4 hh;
        hh[0] = (_Float16)(x.x * cs.x - x.y * cs.y);
        hh[1] = (_Float16)(x.x * cs.y + x.y * cs.x);
        hh[2] = (_Float16)(x.z * cs.z - x.w * cs.w);
        hh[3] = (_Float16)(x.z * cs.w + x.w * cs.z);
        *(f16x4*)(Qs + SW64(p, dq)) = hh;
    }
    __syncthreads();

    // ---- Q fragments from LDS (persistent source), 16 cols per wave ----
    f16x8 qh[2];
    {
        int pr = w * 16 + cl;
#pragma unroll
        for (int ks = 0; ks < 2; ++ks)
            qh[ks] = *(const f16x8*)(Qs + SW64(pr, ks * 32 + g * 8));
    }

    float m0 = -INFINITY, l0 = 0.f;
    f32x4 Oacc[4];
#pragma unroll
    for (int i1 = 0; i1 < 4; ++i1) Oacc[i1] = (f32x4)0.f;

    const float* Kbh = k_in + (size_t)bh * Tt * Dd;
    const float* Vbh = v_in + (size_t)bh * Tt * Dd;

    // ---- prefetch state: K raw f32 + cos/sin fp16 + region ids + V fp16 ----
    float4 kx[2];
    f16x4  kcs16[2];
    int    krg[2], rreg;
    f16x8  vx16;
    auto prefetch = [&](int t0n) {
#pragma unroll
        for (int it = 0; it < 2; ++it) {
            int f   = tid + 512 * it;
            int row = f >> 4;
            int dq  = (f & 15) << 2;
            int fi  = (dq & 31) >> 1;
            kx[it]  = ((const float4*)(Kbh + (size_t)t0n * Dd))[f];
            float4 c = *(const float4*)(postab + (size_t)((t0n + row) * 16 + fi) * 2);
            f16x4 cc;
            cc[0] = (_Float16)c.x; cc[1] = (_Float16)c.y;
            cc[2] = (_Float16)c.z; cc[3] = (_Float16)c.w;
            kcs16[it] = cc;
            krg[it] = regions[b * Tt + t0n + row];
        }
        {
            int dcol = tid & 63;
            int tl   = (tid >> 6) * 8;
#pragma unroll
            for (int r = 0; r < 8; ++r)
                vx16[r] = (_Float16)Vbh[(size_t)(t0n + tl + r) * Dd + dcol];
        }
        rreg = (tid < 64) ? regions[b * Tt + t0n + tid] : 0;
    };
    prefetch(c0);

    for (int tt = 0; tt < NTILE; ++tt) {
        const int t0 = c0 + tt * 64;
        __syncthreads();   // B1: previous tile fully consumed
        if (tid < 64) regs_s[tid] = rreg;

        // ---- convert prefetched K tile: rope fp16 -> LDS (cos/sin from fp16 regs) ----
#pragma unroll
        for (int it = 0; it < 2; ++it) {
            int f   = tid + 512 * it;
            int row = f >> 4;
            int dq  = (f & 15) << 2;
            float4 x = kx[it];
            float4 cs;
            if (dq < 32) {
                f16x4 cc = kcs16[it];
                cs = make_float4((float)cc[0], (float)cc[1], (float)cc[2], (float)cc[3]);
            } else {
                int rg = krg[it];
                cs = *(const float4*)(&rtab[(rg * 16 + ((dq & 31) >> 1)) * 2]);
            }
            f16x4 hh;
            hh[0] = (_Float16)(x.x * cs.x - x.y * cs.y);
            hh[1] = (_Float16)(x.x * cs.y + x.y * cs.x);
            hh[2] = (_Float16)(x.z * cs.z - x.w * cs.w);
            hh[3] = (_Float16)(x.z * cs.w + x.w * cs.z);
            *(f16x4*)(Ks + SW64(row, dq)) = hh;
        }

        // ---- write prefetched V tile (already fp16) -> LDS ----
        {
            int dcol = tid & 63;
            int tl   = (tid >> 6) * 8;
            *(f16x8*)(Vs + SW64(dcol, tl)) = vx16;
        }
        __syncthreads();   // B2: staging complete

        // ---- issue next tile's loads (latency hides under this tile's compute) ----
        if (tt + 1 < NTILE) prefetch(t0 + 64);

        // ---- QK^T MFMA, 2 k-steps (single fp16), setprio-wrapped ----
        f32x4 sacc[4];
#pragma unroll
        for (int mt = 0; mt < 4; ++mt) sacc[mt] = (f32x4)0.f;
        __builtin_amdgcn_s_setprio(1);
#pragma unroll
        for (int s = 0; s < 2; ++s) {
            f16x8 b0 = qh[s];
#pragma unroll
            for (int mt = 0; mt < 4; ++mt) {
                int tr = mt * 16 + cl;
                f16x8 ak = *(const f16x8*)(Ks + SW64(tr, s * 32 + g * 8));
                sacc[mt] = __builtin_amdgcn_mfma_f32_16x16x32_f16(ak, b0, sacc[mt], 0, 0, 0);
            }
        }
        __builtin_amdgcn_s_setprio(0);

        // ---- scale + bias; per-column (p) tile max ----
        float tmax0 = -INFINITY;
        const int ridx0 = ((w * 16 + cl) >> 2) + 1;
#pragma unroll
        for (int mt = 0; mt < 4; ++mt) {
#pragma unroll
            for (int r = 0; r < 4; ++r) {
                int rg = regs_s[mt * 16 + g * 4 + r];
                float s0 = sacc[mt][r] * 0.125f + ((ridx0 == rg) ? bs : bd);
                sacc[mt][r] = s0;
                tmax0 = fmaxf(tmax0, s0);
            }
        }
        tmax0 = fmaxf(tmax0, __shfl_xor(tmax0, 16, 64));
        tmax0 = fmaxf(tmax0, __shfl_xor(tmax0, 32, 64));
        float mn0 = fmaxf(m0, tmax0);
        float sc0 = __expf(m0 - mn0);

        // ---- P = exp(s - m_new) -> fp16 -> LDS (wave-private rows); f32 row sums ----
        float rs0 = 0.f;
#pragma unroll
        for (int mt = 0; mt < 4; ++mt) {
            f16x4 ph0;
#pragma unroll
            for (int r = 0; r < 4; ++r) {
                float e0 = __expf(sacc[mt][r] - mn0);
                rs0 += e0;
                ph0[r] = (_Float16)e0;
            }
            int trow = mt * 16 + g * 4;
            int pa = w * 16 + cl;
            *(f16x4*)(Ps + SW64(pa, trow)) = ph0;
        }
        rs0 += __shfl_xor(rs0, 16, 64); rs0 += __shfl_xor(rs0, 32, 64);
        l0 = l0 * sc0 + rs0; m0 = mn0;

        // P rows are wave-private: drain this wave's LDS writes, no block barrier
        asm volatile("s_waitcnt lgkmcnt(0)" ::: "memory");
        __builtin_amdgcn_sched_barrier(0);

        // ---- rescale O (factor per output row p = w*16 + g*4 + r) ----
#pragma unroll
        for (int r = 0; r < 4; ++r) {
            float f0 = __shfl(sc0, g * 4 + r, 64);
#pragma unroll
            for (int nt = 0; nt < 4; ++nt) Oacc[nt][r] *= f0;
        }

        // ---- PV: O += P·V (fp16, 2 k-steps), setprio-wrapped ----
        __builtin_amdgcn_s_setprio(1);
#pragma unroll
        for (int s = 0; s < 2; ++s) {
            f16x8 ap0;
            {
                int pp = w * 16 + cl;
                ap0 = *(const f16x8*)(Ps + SW64(pp, s * 32 + g * 8));
            }
#pragma unroll
            for (int nt = 0; nt < 4; ++nt) {
                int d = nt * 16 + cl;
                f16x8 bv = *(const f16x8*)(Vs + SW64(d, s * 32 + g * 8));
                Oacc[nt] = __builtin_amdgcn_mfma_f32_16x16x32_f16(ap0, bv, Oacc[nt], 0, 0, 0);
            }
        }
        __builtin_amdgcn_s_setprio(0);
    }

    // ---- write partials (fp16 pO; m,l stay f32) ----
    size_t obase = (size_t)(bh * NS + chunk) * Pp * Dd;
#pragma unroll
    for (int nt = 0; nt < 4; ++nt)
#pragma unroll
        for (int r = 0; r < 4; ++r) {
            int pb = w * 16 + g * 4 + r;
            int d  = nt * 16 + cl;
            pO[obase + pb * 64 + d] = (_Float16)Oacc[nt][r];
        }
    if (g == 0) {
        size_t mlb = (size_t)(bh * NS + chunk) * Pp;
        int p0 = w * 16 + cl;
        *(float2*)(pML + (mlb + p0) * 2) = make_float2(m0, l0);
    }
}

// ---------------- combine partials across T-chunks (vectorized f16x8 loads) ----------------
__global__ void k_combine(const _Float16* __restrict__ pO, const float* __restrict__ pML,
                          float* __restrict__ out, int NS) {
    int bh = blockIdx.x >> 2;
    int pq = blockIdx.x & 3;
    int p  = pq * 32 + (threadIdx.x >> 3);
    int d8 = (threadIdx.x & 7) * 8;

    float M = -INFINITY;
    float mv[8], lv[8];
    for (int c = 0; c < NS; ++c) {
        float2 ml = *(const float2*)(pML + ((size_t)(bh * NS + c) * Pp + p) * 2);
        mv[c] = ml.x; lv[c] = ml.y;
        M = fmaxf(M, ml.x);
    }
    float L = 0.f;
    float o[8];
#pragma unroll
    for (int j = 0; j < 8; ++j) o[j] = 0.f;
    for (int c = 0; c < NS; ++c) {
        float wgt = __expf(mv[c] - M);
        L += wgt * lv[c];
        f16x8 ov = *(const f16x8*)(pO + ((size_t)(bh * NS + c) * Pp + p) * Dd + d8);
#pragma unroll
        for (int j = 0; j < 8; ++j) o[j] += wgt * (float)ov[j];
    }
    float rL = 1.f / L;
    float4 o0 = make_float4(o[0] * rL, o[1] * rL, o[2] * rL, o[3] * rL);
    float4 o1 = make_float4(o[4] * rL, o[5] * rL, o[6] * rL, o[7] * rL);
    float* dst = out + ((size_t)bh * Pp + p) * Dd + d8;
    *(float4*)(dst + 0) = o0;
    *(float4*)(dst + 4) = o1;
}

// ---------------- launcher ----------------
extern "C" void kernel_launch(void* const* d_in, const int* in_sizes, int n_in,
                              void* d_out, int out_size, void* d_ws, size_t ws_size,
                              hipStream_t stream) {
    const float* q         = (const float*)d_in[0];
    const float* k         = (const float*)d_in[1];
    const float* v         = (const float*)d_in[2];
    const int*   regions   = (const int*)d_in[3];
    const float* bias_same = (const float*)d_in[7];
    const float* bias_diff = (const float*)d_in[8];

    float* ws     = (float*)d_ws;
    float* postab = ws;
    float* regtab = postab + Tt * 16 * 2;
    int*   starts = (int*)(regtab + 33 * 16 * 2);
    _Float16* pO  = (_Float16*)(starts + 128);
    size_t fixed_b = (size_t)((char*)pO - (char*)ws);

    int NS = 8;   // grid 512 = 2 blocks/CU resident (52.5 KB LDS)
    while (NS > 1 && fixed_b + (size_t)BHc * NS * Pp * (Dd * 2 + 8) > ws_size) NS >>= 1;
    float* pML = (float*)(pO + (size_t)BHc * NS * Pp * Dd);

    k_prelude<<<dim3(257), dim3(256), 0, stream>>>(regions, postab, regtab, starts);
    k_attn<<<dim3(BHc * NS), dim3(512), 0, stream>>>(q, k, v, regions, bias_same, bias_diff,
                                                     postab, regtab, starts, pO, pML, NS);
    k_combine<<<dim3(BHc * 4), dim3(256), 0, stream>>>(pO, pML, (float*)d_out, NS);
}